// Round 4
// baseline (37.324 us; speedup 1.0000x reference)
//
#include <hip/hip_runtime.h>

#define BATCH   8192
#define NNEIGH  64
#define FEAT    128
#define EMBED   64
#define EPAD    68          // padded s_part stride (68*4B = 17*16B)

// ---------------- kernel 1: per-wave sort + gather + mean -> ws ------------
// One 64-lane wave per batch row. No LDS, no barriers.
//   - bitonic sort (value,index) ascending => jax stable top_k semantics
//   - lanes 0..ns-1 write samp_scores and fetch selected neighbor ids
//   - all 64 lanes gather float2 slices of the 16 selected feature rows,
//     ids broadcast in-wave via __shfl; mean + self written to ws cat rows
__global__ __launch_bounds__(256, 8) void sort_gather_kernel(
    const float* __restrict__ feat,    // [N_NODES, 128]
    const int*   __restrict__ nodes,   // [B]
    const float* __restrict__ bscore,  // [B, 2]
    const float* __restrict__ nscore,  // [B, 64, 2]
    const int*   __restrict__ nids,    // [B, 64]
    const int*   __restrict__ ns_ptr,  // scalar num_sample (16)
    float*       __restrict__ out,     // samp_scores tail section
    float*       __restrict__ ws_cat)  // [B, 256] = [self | agg]
{
    const int row  = (blockIdx.x * blockDim.x + threadIdx.x) >> 6;
    const int lane = threadIdx.x & 63;
    const int ns   = *ns_ptr;

    // self-features load issued early (independent of sort)
    const float2 self = *(const float2*)&feat[(size_t)nodes[row] * FEAT + lane * 2];

    // ---- sort ----
    const float  ctr = bscore[row * 2];
    const float2 sc  = *(const float2*)&nscore[(size_t)(row * NNEIGH + lane) * 2];
    float d   = fabsf(ctr - sc.x);
    int   idx = lane;
    #pragma unroll
    for (int k = 2; k <= 64; k <<= 1) {
        #pragma unroll
        for (int j = k >> 1; j > 0; j >>= 1) {
            const float od = __shfl_xor(d, j);
            const int   oi = __shfl_xor(idx, j);
            const bool up    = ((lane & k) == 0);
            const bool lower = ((lane & j) == 0);
            // lexicographic (value, index) => jax stable top_k tie-break
            const bool oless = (od < d) || (od == d && oi < idx);
            if ((lower == up) ? oless : !oless) { d = od; idx = oi; }
        }
    }

    int gid = 0;
    if (lane < ns) {
        out[(size_t)BATCH * EMBED + (size_t)row * ns + lane] = d;
        gid = nids[row * NNEIGH + idx];     // selected neighbor id, rank=lane
    }

    // ---- gather + mean (float2 per lane; 512B per row per instruction) ----
    float2 acc = make_float2(0.f, 0.f);
    if (ns == 16) {
        #pragma unroll
        for (int j = 0; j < 16; ++j) {
            const int id = __shfl(gid, j);
            const float2 v = *(const float2*)&feat[(size_t)id * FEAT + lane * 2];
            acc.x += v.x; acc.y += v.y;
        }
    } else {
        for (int j = 0; j < ns; ++j) {
            const int id = __shfl(gid, j);
            const float2 v = *(const float2*)&feat[(size_t)id * FEAT + lane * 2];
            acc.x += v.x; acc.y += v.y;
        }
    }
    const float inv_ns = 1.0f / (float)ns;
    acc.x *= inv_ns; acc.y *= inv_ns;

    *(float2*)&ws_cat[(size_t)row * 2 * FEAT + lane * 2]        = self;
    *(float2*)&ws_cat[(size_t)row * 2 * FEAT + FEAT + lane * 2] = acc;
}

// ---------------- kernel 2: cat[8192,256] @ W[256,64] + ReLU ---------------
// 16 rows per block (grid 512). split-k over waves (4 x 64k); thread computes
// a 4-row x 4-col tile; W float4 shared across the 4 rows in registers,
// wave-level address dedup keeps W traffic at 64KB/block.
__global__ __launch_bounds__(256, 4) void matmul_kernel(
    const float* __restrict__ ws_cat,  // [B, 256]
    const float* __restrict__ W,       // [256, 64]
    float*       __restrict__ out)     // [B, 64]
{
    const int b0  = blockIdx.x * 16;
    const int tid = threadIdx.x;
    const int q   = tid & 15;          // 4-col group
    const int rq  = (tid >> 4) & 3;    // 4-row quad
    const int ks  = tid >> 6;          // k-chunk of 64
    const int k0  = ks * 64;

    __shared__ float s_part[4][16][EPAD];

    float4 acc[4];
    #pragma unroll
    for (int r = 0; r < 4; ++r) acc[r] = make_float4(0.f, 0.f, 0.f, 0.f);

    #pragma unroll 4
    for (int kk = 0; kk < 64; kk += 4) {
        const int k = k0 + kk;
        float4 cv[4];
        #pragma unroll
        for (int r = 0; r < 4; ++r)
            cv[r] = *(const float4*)&ws_cat[(size_t)(b0 + rq * 4 + r) * 256 + k];
        #pragma unroll
        for (int t = 0; t < 4; ++t) {
            const float4 w4 = *(const float4*)&W[(size_t)(k + t) * EMBED + q * 4];
            #pragma unroll
            for (int r = 0; r < 4; ++r) {
                const float cf = (t == 0) ? cv[r].x : (t == 1) ? cv[r].y
                               : (t == 2) ? cv[r].z : cv[r].w;
                acc[r].x += cf * w4.x; acc[r].y += cf * w4.y;
                acc[r].z += cf * w4.z; acc[r].w += cf * w4.w;
            }
        }
    }
    #pragma unroll
    for (int r = 0; r < 4; ++r)
        *(float4*)&s_part[ks][rq * 4 + r][q * 4] = acc[r];

    __syncthreads();

    {
        const int r2 = tid >> 4;          // 0..15
        const int qq = tid & 15;
        float4 o = make_float4(0.f, 0.f, 0.f, 0.f);
        #pragma unroll
        for (int p = 0; p < 4; ++p) {
            const float4 v = *(const float4*)&s_part[p][r2][qq * 4];
            o.x += v.x; o.y += v.y; o.z += v.z; o.w += v.w;
        }
        o.x = fmaxf(o.x, 0.f); o.y = fmaxf(o.y, 0.f);
        o.z = fmaxf(o.z, 0.f); o.w = fmaxf(o.w, 0.f);
        *(float4*)&out[(size_t)(b0 + r2) * EMBED + qq * 4] = o;
    }
}

extern "C" void kernel_launch(void* const* d_in, const int* in_sizes, int n_in,
                              void* d_out, int out_size, void* d_ws, size_t ws_size,
                              hipStream_t stream) {
    const float* feat   = (const float*)d_in[0];
    const float* W      = (const float*)d_in[1];
    const int*   nodes  = (const int*)d_in[2];
    const float* bscore = (const float*)d_in[3];
    const float* nscore = (const float*)d_in[4];
    const int*   nids   = (const int*)d_in[5];
    const int*   nsamp  = (const int*)d_in[6];
    float* out    = (float*)d_out;
    float* ws_cat = (float*)d_ws;      // 8192*256*4 = 8 MB scratch

    // k1: one wave per row -> 8192 waves -> 2048 blocks of 256 threads
    sort_gather_kernel<<<BATCH / 4, 256, 0, stream>>>(feat, nodes, bscore,
                                                      nscore, nids, nsamp,
                                                      out, ws_cat);
    // k2: 16 rows per block
    matmul_kernel<<<BATCH / 16, 256, 0, stream>>>(ws_cat, W, out);
}

// Round 5
// 23.905 us; speedup vs baseline: 1.5613x; 1.5613x over previous
//
#include <hip/hip_runtime.h>

#define BATCH   8192
#define NNEIGH  64
#define FEAT    128
#define EMBED   64
#define ROWS    8           // batch rows per block
#define CATP    260         // padded cat row stride (floats), 260*4B: b128-aligned, bank-spread
#define EPAD    68          // padded s_part stride (68*4B = 17*16B)
#define KCH     8           // split-k chunks of 32

// 256 threads = 4 waves per block, 8 rows per block, grid = 1024.
// Wave w owns rows 2w, 2w+1 end-to-end through sort+gather (no barrier, no s_sel):
//   P1: self-feat float4 load issued first (in flight during sort).
//   P2: two interleaved 64-lane bitonic sorts (stable (value,index) order).
//   P3: gather: lanes 0-31 -> row A, lanes 32-63 -> row B, float4/lane
//       => 1KB per instruction; 16 unrolled independent loads; ids via __shfl.
//   P4 (after single barrier): split-k matmul, 4x4 register tile per thread,
//       LDS k-reduction + ReLU (identical to round-3 proven phases).
__global__ __launch_bounds__(256, 4) void intra_agg_kernel(
    const float* __restrict__ feat,    // [N_NODES, 128]
    const float* __restrict__ W,       // [256, 64]
    const int*   __restrict__ nodes,   // [B]
    const float* __restrict__ bscore,  // [B, 2]
    const float* __restrict__ nscore,  // [B, 64, 2]
    const int*   __restrict__ nids,    // [B, 64]
    const int*   __restrict__ ns_ptr,  // scalar num_sample (16)
    float*       __restrict__ out)     // [B*64] to_feats ++ [B*ns] samp_scores
{
    const int b0   = blockIdx.x * ROWS;
    const int tid  = threadIdx.x;
    const int lane = tid & 63;
    const int wave = tid >> 6;
    const int ns   = *ns_ptr;

    __shared__ float s_cat[ROWS * CATP];
    __shared__ float s_part[KCH][ROWS][EPAD];

    const int r0   = wave * 2;        // wave's first local row
    const int half = lane >> 5;       // 0 -> row r0, 1 -> row r0+1
    const int c    = lane & 31;       // float4 chunk within 128-wide feature row

    // ---- earliest: self features for both rows (one 1KB instruction) ------
    const int    selfnode = nodes[b0 + r0 + half];
    const float4 self4    = *(const float4*)&feat[(size_t)selfnode * FEAT + c * 4];

    // ---- sort inputs ------------------------------------------------------
    float d[2];
    int   idx[2];
    #pragma unroll
    for (int i = 0; i < 2; ++i) {
        const int row = b0 + r0 + i;
        const float  ctr = bscore[row * 2];
        const float2 sc  = *(const float2*)&nscore[(size_t)(row * NNEIGH + lane) * 2];
        d[i]   = fabsf(ctr - sc.x);
        idx[i] = lane;
    }
    // ---- two interleaved bitonic sorts (stable lexicographic) -------------
    #pragma unroll
    for (int k = 2; k <= 64; k <<= 1) {
        #pragma unroll
        for (int j = k >> 1; j > 0; j >>= 1) {
            #pragma unroll
            for (int i = 0; i < 2; ++i) {
                const float od = __shfl_xor(d[i], j);
                const int   oi = __shfl_xor(idx[i], j);
                const bool up    = ((lane & k) == 0);
                const bool lower = ((lane & j) == 0);
                // lexicographic (value, index) => jax stable top_k tie-break
                const bool oless = (od < d[i]) || (od == d[i] && oi < idx[i]);
                if ((lower == up) ? oless : !oless) { d[i] = od; idx[i] = oi; }
            }
        }
    }
    // ---- samp_scores + selected ids --------------------------------------
    int gid[2] = {0, 0};
    #pragma unroll
    for (int i = 0; i < 2; ++i) {
        const int row = b0 + r0 + i;
        if (lane < ns) {
            out[(size_t)BATCH * EMBED + (size_t)row * ns + lane] = d[i];
            gid[i] = nids[row * NNEIGH + idx[i]];
        }
    }

    // ---- gather + mean: both rows per instruction (1KB), ids via shfl -----
    float4 a = make_float4(0.f, 0.f, 0.f, 0.f);
    if (ns == 16) {
        #pragma unroll
        for (int j = 0; j < 16; ++j) {
            const int id0 = __shfl(gid[0], j);
            const int id1 = __shfl(gid[1], j);
            const int id  = half ? id1 : id0;
            const float4 v = *(const float4*)&feat[(size_t)id * FEAT + c * 4];
            a.x += v.x; a.y += v.y; a.z += v.z; a.w += v.w;
        }
    } else {
        for (int j = 0; j < ns; ++j) {
            const int id0 = __shfl(gid[0], j);
            const int id1 = __shfl(gid[1], j);
            const int id  = half ? id1 : id0;
            const float4 v = *(const float4*)&feat[(size_t)id * FEAT + c * 4];
            a.x += v.x; a.y += v.y; a.z += v.z; a.w += v.w;
        }
    }
    const float inv_ns = 1.0f / (float)ns;
    a.x *= inv_ns; a.y *= inv_ns; a.z *= inv_ns; a.w *= inv_ns;

    {
        const int r = r0 + half;
        *(float4*)&s_cat[r * CATP + c * 4]        = self4;  // conflict-free b128
        *(float4*)&s_cat[r * CATP + FEAT + c * 4] = a;
    }
    __syncthreads();

    // ---------------- split-k matmul, (4 rows x 4 cols) tile ---------------
    {
        const int q  = tid & 15;          // 4-col group of W/out
        const int rq = (tid >> 4) & 1;    // row-quad: rows rq*4 .. rq*4+3
        const int ks = tid >> 5;          // k-chunk of 32 (0..7)
        const int k0 = ks * 32;

        float4 acc[4];
        #pragma unroll
        for (int r = 0; r < 4; ++r) acc[r] = make_float4(0.f, 0.f, 0.f, 0.f);

        #pragma unroll
        for (int kk = 0; kk < 32; kk += 4) {
            const int k = k0 + kk;
            float4 cv[4];
            #pragma unroll
            for (int r = 0; r < 4; ++r)
                cv[r] = *(const float4*)&s_cat[(rq * 4 + r) * CATP + k]; // broadcast
            #pragma unroll
            for (int t = 0; t < 4; ++t) {
                const float4 w4 = *(const float4*)&W[(size_t)(k + t) * EMBED + q * 4];
                #pragma unroll
                for (int r = 0; r < 4; ++r) {
                    const float cf = (t == 0) ? cv[r].x : (t == 1) ? cv[r].y
                                   : (t == 2) ? cv[r].z : cv[r].w;
                    acc[r].x += cf * w4.x; acc[r].y += cf * w4.y;
                    acc[r].z += cf * w4.z; acc[r].w += cf * w4.w;
                }
            }
        }
        #pragma unroll
        for (int r = 0; r < 4; ++r)
            *(float4*)&s_part[ks][rq * 4 + r][q * 4] = acc[r];
    }
    __syncthreads();

    // ---------------- reduce k-chunks, ReLU, store -------------------------
    if (tid < ROWS * 16) {
        const int r2 = tid >> 4;          // 0..7
        const int q  = tid & 15;
        float4 o = make_float4(0.f, 0.f, 0.f, 0.f);
        #pragma unroll
        for (int p = 0; p < KCH; ++p) {
            const float4 v = *(const float4*)&s_part[p][r2][q * 4];
            o.x += v.x; o.y += v.y; o.z += v.z; o.w += v.w;
        }
        o.x = fmaxf(o.x, 0.f); o.y = fmaxf(o.y, 0.f);
        o.z = fmaxf(o.z, 0.f); o.w = fmaxf(o.w, 0.f);
        *(float4*)&out[(size_t)(b0 + r2) * EMBED + q * 4] = o;
    }
}

extern "C" void kernel_launch(void* const* d_in, const int* in_sizes, int n_in,
                              void* d_out, int out_size, void* d_ws, size_t ws_size,
                              hipStream_t stream) {
    const float* feat   = (const float*)d_in[0];
    const float* W      = (const float*)d_in[1];
    const int*   nodes  = (const int*)d_in[2];
    const float* bscore = (const float*)d_in[3];
    const float* nscore = (const float*)d_in[4];
    const int*   nids   = (const int*)d_in[5];
    const int*   nsamp  = (const int*)d_in[6];
    float* out = (float*)d_out;

    intra_agg_kernel<<<BATCH / ROWS, 256, 0, stream>>>(feat, W, nodes, bscore,
                                                       nscore, nids, nsamp, out);
}